// Round 16
// baseline (516.248 us; speedup 1.0000x reference)
//
#include <hip/hip_runtime.h>

// ---- static configuration (mirrors reference) ----
#define N_SHOTS 8
#define NZP 304
#define NXP 304
#define NT 50
#define N_REC 300
#define FLAT (NZP * NXP)          // 92416
#define DT 0.001f
#define INV_DX 0.25f
#define INV_DX2 0.0625f

#define C23 (2.0f / 3.0f)
#define C112 (1.0f / 12.0f)
#define C43 (4.0f / 3.0f)

#define RR 8                      // output rows per block
#define AR 12                     // step-A rows (RR + 4 halo)

union F4 { float4 v; float f[4]; };
__device__ __forceinline__ F4 ldf4(const float* p) {
    F4 r; r.v = *reinterpret_cast<const float4*>(p); return r;
}
__device__ __forceinline__ F4 zf4() {
    F4 r; r.v = make_float4(0.f, 0.f, 0.f, 0.f); return r;
}

// Two FDTD steps per launch. Block = (shot, g): 8 output rows z0=g*8..+8 of
// one shot, full 304-wide rows (x-halo complete in-block; only z-halo ±2).
// Step A: compute t+1 on 12 rows -> LDS {w1, az*psiz, ax*psix, az*zetaz,
// ax*zetax} (products are what step B and the state updates consume).
// Step B: compute t+2 on the 8 owned rows from LDS. Blocks are fully
// independent within a launch: wavefield uses 4 rotating buffers, psi and
// zeta are double-buffered (in read-only, out write-only -> no races).
// shot = bid&7 pins each shot to one XCD (R7-proven). 1.25x arithmetic
// amplification buys half the graph nodes (launch overhead dominates).
__global__ __launch_bounds__(320) void fdtd_step2(
    const float* __restrict__ v,
    const float* __restrict__ amp,        // (NT, N_SHOTS, 1)
    const float* __restrict__ az, const float* __restrict__ bz, const float* __restrict__ dbz,
    const float* __restrict__ ax, const float* __restrict__ bx, const float* __restrict__ dbx,
    const int* __restrict__ src_i,
    const int* __restrict__ rec_i,
    const float* __restrict__ wc,         // w_t      (read-only)
    const float* __restrict__ wp,         // w_{t-1}  (read-only)
    float* __restrict__ w1g,              // out w_{t+1} (next wp)
    float* __restrict__ w2g,              // out w_{t+2} (next wc)
    const float* __restrict__ pzi, float* __restrict__ pzo,
    const float* __restrict__ pxi, float* __restrict__ pxo,
    const float* __restrict__ zzi, float* __restrict__ zzo,
    const float* __restrict__ zxi, float* __restrict__ zxo,
    float* __restrict__ rec_out,          // (NT, N_SHOTS, N_REC)
    int t)
{
    __shared__ float w1s[AR][NXP];        // w at t+1
    __shared__ float qzs[AR][NXP];        // az * psi_z(t+1)
    __shared__ float qxs[RR][NXP];        // ax * psi_x(t+1)   (owned rows)
    __shared__ float azzs[RR][NXP];       // az * zeta_z(t+1)  (owned rows)
    __shared__ float azxs[RR][NXP];       // ax * zeta_x(t+1)  (owned rows)

    const int bid = blockIdx.x;
    const int shot = bid & 7;
    const int g = bid >> 3;               // 0..37
    const int tid = threadIdx.x;
    const int z0 = g * RR;
    const int srci = src_i[shot];
    const int sbase = shot * FLAT;

    if (tid >= 304) {
        // records at time t: pre-step wavefield (global)
        if (g < 19) {
            int ridx = g * 16 + (tid - 304);
            if (ridx < N_REC)
                rec_out[t * (N_SHOTS * N_REC) + shot * N_REC + ridx] =
                    wc[sbase + rec_i[shot * N_REC + ridx]];
        }
    } else {
        const float ampA = amp[t * N_SHOTS + shot];
        const int r4 = tid / 76;
        const int i = tid - r4 * 76;
        const int x0 = 4 * i;
        const bool lok = (i > 0), rok = (i < 75);

        for (int ra = 0; ra < 3; ++ra) {
            const int la = r4 + 4 * ra;   // 0..11, each exactly once per block
            const int zA = z0 - 2 + la;
            if (zA < 0 || zA >= NZP) {    // only halo rows can be off-grid
                *reinterpret_cast<float4*>(&w1s[la][x0]) = make_float4(0,0,0,0);
                *reinterpret_cast<float4*>(&qzs[la][x0]) = make_float4(0,0,0,0);
                continue;
            }
            const int idx = sbase + zA * NXP + x0;

            // x-direction 12-wide windows of wc and (ax*pxi)
            F4 wCx = ldf4(wc + idx);
            F4 wLx = lok ? ldf4(wc + idx - 4) : zf4();
            F4 wRx = rok ? ldf4(wc + idx + 4) : zf4();
            F4 pCx = ldf4(pxi + idx);
            F4 pLx = lok ? ldf4(pxi + idx - 4) : zf4();
            F4 pRx = rok ? ldf4(pxi + idx + 4) : zf4();
            F4 aCx = ldf4(ax + x0);
            F4 aLx = lok ? ldf4(ax + x0 - 4) : zf4();
            F4 aRx = rok ? ldf4(ax + x0 + 4) : zf4();
            float wxw[12], apx[12];
            #pragma unroll
            for (int k = 0; k < 4; ++k) {
                wxw[k]     = wLx.f[k];  apx[k]     = aLx.f[k] * pLx.f[k];
                wxw[4 + k] = wCx.f[k];  apx[4 + k] = aCx.f[k] * pCx.f[k];
                wxw[8 + k] = wRx.f[k];  apx[8 + k] = aRx.f[k] * pRx.f[k];
            }

            // z-direction neighbors (global, guarded)
            const bool m1 = (zA >= 1), m2 = (zA >= 2), p1 = (zA < NZP - 1), p2 = (zA < NZP - 2);
            F4 wzm1 = m1 ? ldf4(wc + idx - NXP)     : zf4();
            F4 wzm2 = m2 ? ldf4(wc + idx - 2 * NXP) : zf4();
            F4 wzp1 = p1 ? ldf4(wc + idx + NXP)     : zf4();
            F4 wzp2 = p2 ? ldf4(wc + idx + 2 * NXP) : zf4();
            const float azm1 = m1 ? az[zA - 1] : 0.f;
            const float azm2 = m2 ? az[zA - 2] : 0.f;
            const float azp1 = p1 ? az[zA + 1] : 0.f;
            const float azp2 = p2 ? az[zA + 2] : 0.f;
            F4 qzm1 = m1 ? ldf4(pzi + idx - NXP)     : zf4();
            F4 qzm2 = m2 ? ldf4(pzi + idx - 2 * NXP) : zf4();
            F4 qzp1 = p1 ? ldf4(pzi + idx + NXP)     : zf4();
            F4 qzp2 = p2 ? ldf4(pzi + idx + 2 * NXP) : zf4();
            #pragma unroll
            for (int k = 0; k < 4; ++k) {
                qzm1.f[k] *= azm1; qzm2.f[k] *= azm2;
                qzp1.f[k] *= azp1; qzp2.f[k] *= azp2;
            }

            F4 pzC = ldf4(pzi + idx);
            F4 zzC = ldf4(zzi + idx);
            F4 zxC = ldf4(zxi + idx);
            F4 vC  = ldf4(v + zA * NXP + x0);
            F4 wpC = ldf4(wp + idx);
            F4 bxC = ldf4(bx + x0);
            F4 dxC = ldf4(dbx + x0);
            const float azc = az[zA], bzc = bz[zA], dbzc = dbz[zA];

            F4 o_w1, o_qz, o_qx, o_azz, o_azx;
            #pragma unroll
            for (int k = 0; k < 4; ++k) {
                const float c = wxw[4 + k];
                const float d1x  = ((wxw[5+k] - wxw[3+k]) * C23 + (wxw[2+k] - wxw[6+k]) * C112) * INV_DX;
                const float d2x  = (-2.5f * c + C43 * (wxw[5+k] + wxw[3+k]) - C112 * (wxw[6+k] + wxw[2+k])) * INV_DX2;
                const float dapx = ((apx[5+k] - apx[3+k]) * C23 + (apx[2+k] - apx[6+k]) * C112) * INV_DX;
                const float d1z  = ((wzp1.f[k] - wzm1.f[k]) * C23 + (wzm2.f[k] - wzp2.f[k]) * C112) * INV_DX;
                const float d2z  = (-2.5f * c + C43 * (wzp1.f[k] + wzm1.f[k]) - C112 * (wzp2.f[k] + wzm2.f[k])) * INV_DX2;
                const float dapz = ((qzp1.f[k] - qzm1.f[k]) * C23 + (qzm2.f[k] - qzp2.f[k]) * C112) * INV_DX;

                const float tmpz = (1.f + bzc) * d2z + dbzc * d1z + dapz;
                float w_sum = (1.f + bzc) * tmpz + azc * zzC.f[k];
                const float bxk = bxC.f[k], axk = aCx.f[k];
                const float tmpx = (1.f + bxk) * d2x + dxC.f[k] * d1x + dapx;
                w_sum += (1.f + bxk) * tmpx + axk * zxC.f[k];

                const float vv = vC.f[k];
                float wn = (vv * vv) * (DT * DT) * w_sum + 2.f * c - wpC.f[k];
                if (zA * NXP + x0 + k == srci) wn += ampA;   // inject in halo too

                o_w1.f[k]  = wn;
                const float psiz = bzc * d1z + azc * pzC.f[k];
                o_qz.f[k]  = azc * psiz;
                const float psix = bxk * d1x + apx[4 + k];
                o_qx.f[k]  = axk * psix;
                const float ztz  = bzc * tmpz + azc * zzC.f[k];
                o_azz.f[k] = azc * ztz;
                const float ztx  = bxk * tmpx + axk * zxC.f[k];
                o_azx.f[k] = axk * ztx;
            }
            *reinterpret_cast<float4*>(&w1s[la][x0]) = o_w1.v;
            *reinterpret_cast<float4*>(&qzs[la][x0]) = o_qz.v;
            if (la >= 2 && la < 10) {
                *reinterpret_cast<float4*>(&qxs[la - 2][x0])  = o_qx.v;
                *reinterpret_cast<float4*>(&azzs[la - 2][x0]) = o_azz.v;
                *reinterpret_cast<float4*>(&azxs[la - 2][x0]) = o_azx.v;
                *reinterpret_cast<float4*>(w1g + idx) = o_w1.v;   // owned row
            }
        }
    }

    __syncthreads();

    if (tid < 304) {
        const float ampB = amp[(t + 1) * N_SHOTS + shot];
        const int r4 = tid / 76;
        const int i = tid - r4 * 76;
        const int x0 = 4 * i;
        const bool lok = (i > 0), rok = (i < 75);

        for (int rb = 0; rb < 2; ++rb) {
            const int lo = r4 + 4 * rb;   // 0..7
            const int la = lo + 2;
            const int z = z0 + lo;
            const int idx = sbase + z * NXP + x0;

            F4 wC = ldf4(&w1s[la][x0]);
            F4 wL = lok ? ldf4(&w1s[la][x0 - 4]) : zf4();
            F4 wR = rok ? ldf4(&w1s[la][x0 + 4]) : zf4();
            F4 qC = ldf4(&qxs[lo][x0]);
            F4 qL = lok ? ldf4(&qxs[lo][x0 - 4]) : zf4();
            F4 qR = rok ? ldf4(&qxs[lo][x0 + 4]) : zf4();
            float wxw[12], apx[12];
            #pragma unroll
            for (int k = 0; k < 4; ++k) {
                wxw[k]     = wL.f[k];  apx[k]     = qL.f[k];
                wxw[4 + k] = wC.f[k];  apx[4 + k] = qC.f[k];
                wxw[8 + k] = wR.f[k];  apx[8 + k] = qR.f[k];
            }
            F4 wzm1 = ldf4(&w1s[la - 1][x0]);
            F4 wzm2 = ldf4(&w1s[la - 2][x0]);
            F4 wzp1 = ldf4(&w1s[la + 1][x0]);
            F4 wzp2 = ldf4(&w1s[la + 2][x0]);
            F4 qzm1 = ldf4(&qzs[la - 1][x0]);
            F4 qzm2 = ldf4(&qzs[la - 2][x0]);
            F4 qzp1 = ldf4(&qzs[la + 1][x0]);
            F4 qzp2 = ldf4(&qzs[la + 2][x0]);
            F4 qzC  = ldf4(&qzs[la][x0]);
            F4 azzC = ldf4(&azzs[lo][x0]);
            F4 azxC = ldf4(&azxs[lo][x0]);
            F4 vC   = ldf4(v + z * NXP + x0);
            F4 wold = ldf4(wc + idx);           // w_t acts as wfp for step B
            F4 bxC  = ldf4(bx + x0);
            F4 dxC  = ldf4(dbx + x0);
            const float azc = az[z], bzc = bz[z], dbzc = dbz[z];

            F4 o_w2, o_pz, o_px, o_zz, o_zx;
            #pragma unroll
            for (int k = 0; k < 4; ++k) {
                const float c = wxw[4 + k];
                const float d1x  = ((wxw[5+k] - wxw[3+k]) * C23 + (wxw[2+k] - wxw[6+k]) * C112) * INV_DX;
                const float d2x  = (-2.5f * c + C43 * (wxw[5+k] + wxw[3+k]) - C112 * (wxw[6+k] + wxw[2+k])) * INV_DX2;
                const float dapx = ((apx[5+k] - apx[3+k]) * C23 + (apx[2+k] - apx[6+k]) * C112) * INV_DX;
                const float d1z  = ((wzp1.f[k] - wzm1.f[k]) * C23 + (wzm2.f[k] - wzp2.f[k]) * C112) * INV_DX;
                const float d2z  = (-2.5f * c + C43 * (wzp1.f[k] + wzm1.f[k]) - C112 * (wzp2.f[k] + wzm2.f[k])) * INV_DX2;
                const float dapz = ((qzp1.f[k] - qzm1.f[k]) * C23 + (qzm2.f[k] - qzp2.f[k]) * C112) * INV_DX;

                const float tmpz = (1.f + bzc) * d2z + dbzc * d1z + dapz;
                float w_sum = (1.f + bzc) * tmpz + azzC.f[k];
                const float bxk = bxC.f[k];
                const float tmpx = (1.f + bxk) * d2x + dxC.f[k] * d1x + dapx;
                w_sum += (1.f + bxk) * tmpx + azxC.f[k];

                const float vv = vC.f[k];
                float wn = (vv * vv) * (DT * DT) * w_sum + 2.f * c - wold.f[k];
                if (z * NXP + x0 + k == srci) wn += ampB;

                o_w2.f[k] = wn;
                o_pz.f[k] = bzc * d1z + qzC.f[k];
                o_px.f[k] = bxk * d1x + qC.f[k];
                o_zz.f[k] = bzc * tmpz + azzC.f[k];
                o_zx.f[k] = bxk * tmpx + azxC.f[k];
            }
            *reinterpret_cast<float4*>(w2g + idx) = o_w2.v;
            *reinterpret_cast<float4*>(pzo + idx) = o_pz.v;
            *reinterpret_cast<float4*>(pxo + idx) = o_px.v;
            *reinterpret_cast<float4*>(zzo + idx) = o_zz.v;
            *reinterpret_cast<float4*>(zxo + idx) = o_zx.v;
        }
    }

    // records at time t+1: from LDS w1 (owning block only; no extra barrier
    // needed — w1s is not modified after the sync above)
    if (tid < N_REC) {
        const int rc = rec_i[shot * N_REC + tid];
        const int rz = rc / NXP;
        if (rz >= z0 && rz < z0 + RR) {
            rec_out[(t + 1) * (N_SHOTS * N_REC) + shot * N_REC + tid] =
                w1s[rz - z0 + 2][rc - rz * NXP];
        }
    }
}

extern "C" void kernel_launch(void* const* d_in, const int* in_sizes, int n_in,
                              void* d_out, int out_size, void* d_ws, size_t ws_size,
                              hipStream_t stream) {
    const float* v     = (const float*)d_in[0];
    const float* amp   = (const float*)d_in[1];
    const float* az    = (const float*)d_in[2];
    const float* bz    = (const float*)d_in[3];
    const float* dbz   = (const float*)d_in[4];
    const float* ax    = (const float*)d_in[5];
    const float* bx    = (const float*)d_in[6];
    const float* dbx   = (const float*)d_in[7];
    const int* src_i   = (const int*)d_in[8];
    const int* rec_i   = (const int*)d_in[9];
    float* out = (float*)d_out;

    float* ws = (float*)d_ws;
    const size_t A = (size_t)N_SHOTS * FLAT;

    // 12 state arrays. First 6 (the t=0 inputs) are zeroed; the 6 outputs are
    // fully written each kernel before being read by the next.
    float* X   = ws + 0 * A;   // w_t
    float* Y   = ws + 1 * A;   // w_{t-1}
    float* PZI = ws + 2 * A;   float* PXI = ws + 3 * A;
    float* ZZI = ws + 4 * A;   float* ZXI = ws + 5 * A;
    float* Z   = ws + 6 * A;   // out w_{t+1}
    float* W   = ws + 7 * A;   // out w_{t+2}
    float* PZO = ws + 8 * A;   float* PXO = ws + 9 * A;
    float* ZZO = ws + 10 * A;  float* ZXO = ws + 11 * A;

    hipMemsetAsync(d_ws, 0, 6 * A * sizeof(float), stream);

    for (int k = 0; k < NT / 2; ++k) {
        fdtd_step2<<<N_SHOTS * (NZP / RR), 320, 0, stream>>>(
            v, amp, az, bz, dbz, ax, bx, dbx, src_i, rec_i,
            X, Y, Z, W,
            PZI, PZO, PXI, PXO, ZZI, ZZO, ZXI, ZXO,
            out, 2 * k);
        // rotate: next (wc, wp) = (w_{t+2}, w_{t+1}); old inputs become scratch
        float* oX = X; float* oY = Y;
        X = W; Y = Z; Z = oX; W = oY;
        float* tp;
        tp = PZI; PZI = PZO; PZO = tp;
        tp = PXI; PXI = PXO; PXO = tp;
        tp = ZZI; ZZI = ZZO; ZZO = tp;
        tp = ZXI; ZXI = ZXO; ZXO = tp;
    }
}

// Round 17
// 415.314 us; speedup vs baseline: 1.2430x; 1.2430x over previous
//
#include <hip/hip_runtime.h>

// ---- static configuration (mirrors reference) ----
#define N_SHOTS 8
#define NZP 304
#define NXP 304
#define NT 50
#define N_REC 300
#define FLAT (NZP * NXP)          // 92416
#define DT 0.001f
#define INV_DX 0.25f
#define INV_DX2 0.0625f

#define C23 (2.0f / 3.0f)
#define C112 (1.0f / 12.0f)
#define C43 (4.0f / 3.0f)

#define NCH 361                   // chunks per block = 76*304/64

union F4 { float4 v; float f[4]; };
__device__ __forceinline__ F4 ldf4(const float* p) {
    F4 r; r.v = *reinterpret_cast<const float4*>(p); return r;
}
__device__ __forceinline__ F4 zf4() {
    F4 r; r.v = make_float4(0.f, 0.f, 0.f, 0.f); return r;
}

// One FDTD step, float4-vectorized, perfectly load-balanced.
// Shot grid = 76x304 = 23104 four-cell chunks (chunks never span a row).
// Grid = 512 blocks = EXACTLY 2 blocks/CU (64 blocks/shot, shot=bid&7 pins
// each shot to one XCD - R7-proven). Each block owns exactly NCH=361 chunks:
// pass 0 = 304 chunks (tid<304), pass 1 = 57 chunks (tid<57). All blocks
// identical -> no CU runs a 3rd block round (R11's 608-block grid had 96 CUs
// doing 3 blocks while 160 did 2 -> 79% CU efficiency; this is ~98%).
__global__ __launch_bounds__(320) void fdtd_step4(
    const float* __restrict__ v,
    const float* __restrict__ amp,        // (NT, N_SHOTS, 1)
    const float* __restrict__ az, const float* __restrict__ bz, const float* __restrict__ dbz,
    const float* __restrict__ ax, const float* __restrict__ bx, const float* __restrict__ dbx,
    const int* __restrict__ src_i,
    const int* __restrict__ rec_i,
    const float* __restrict__ wc,         // current wavefield (read-only)
    float* __restrict__ wp,               // prev wavefield; overwritten with new
    const float* __restrict__ pzi, float* __restrict__ pzo,
    const float* __restrict__ pxi, float* __restrict__ pxo,
    float* __restrict__ zz, float* __restrict__ zx,
    float* __restrict__ rec_out,          // (NT, N_SHOTS, N_REC)
    int t)
{
    const int bid = blockIdx.x;
    const int shot = bid & 7;
    const int j = bid >> 3;               // 0..63
    const int tid = threadIdx.x;
    const int sbase = shot * FLAT;

    if (tid >= NXP) {
        // receiver gather from pre-step wc (same shot -> same XCD)
        if (j < 19) {
            int ridx = j * 16 + (tid - NXP);
            if (ridx < N_REC) {
                rec_out[t * (N_SHOTS * N_REC) + shot * N_REC + ridx] =
                    wc[sbase + rec_i[shot * N_REC + ridx]];
            }
        }
        return;
    }

    const int srci = src_i[shot];
    const float amp_t = amp[t * N_SHOTS + shot];
    const int chbase = j * NCH;

    #pragma unroll
    for (int p = 0; p < 2; ++p) {
        const int chl = tid + 304 * p;
        if (p == 1 && tid >= NCH - 304) break;   // pass 1: tid < 57
        const int ch = chbase + chl;             // global chunk in [0, 23104)
        const int z = ch / 76;
        const int i = ch - z * 76;               // x-chunk 0..75
        const int x0 = 4 * i;
        const int idx = sbase + 4 * ch;          // = sbase + z*NXP + x0

        // ---- x-direction: 12-wide windows of wc and (ax*pxi) ----
        const bool lok = (i > 0), rok = (i < 75);
        F4 wCx = ldf4(wc + idx);
        F4 wLx = lok ? ldf4(wc + idx - 4) : zf4();
        F4 wRx = rok ? ldf4(wc + idx + 4) : zf4();
        F4 pCx = ldf4(pxi + idx);
        F4 pLx = lok ? ldf4(pxi + idx - 4) : zf4();
        F4 pRx = rok ? ldf4(pxi + idx + 4) : zf4();
        F4 aCx = ldf4(ax + x0);
        F4 aLx = lok ? ldf4(ax + x0 - 4) : zf4();
        F4 aRx = rok ? ldf4(ax + x0 + 4) : zf4();

        float wx[12], apx[12];
        #pragma unroll
        for (int k = 0; k < 4; ++k) {
            wx[k]     = wLx.f[k];  apx[k]     = aLx.f[k] * pLx.f[k];
            wx[4 + k] = wCx.f[k];  apx[4 + k] = aCx.f[k] * pCx.f[k];
            wx[8 + k] = wRx.f[k];  apx[8 + k] = aRx.f[k] * pRx.f[k];
        }

        // ---- z-direction: neighbor rows (guarded, zero outside) ----
        const bool m1 = (z >= 1), m2 = (z >= 2), p1 = (z < NZP - 1), p2 = (z < NZP - 2);
        F4 wzm1 = m1 ? ldf4(wc + idx - NXP)     : zf4();
        F4 wzm2 = m2 ? ldf4(wc + idx - 2 * NXP) : zf4();
        F4 wzp1 = p1 ? ldf4(wc + idx + NXP)     : zf4();
        F4 wzp2 = p2 ? ldf4(wc + idx + 2 * NXP) : zf4();
        const float azm1 = m1 ? az[z - 1] : 0.f;
        const float azm2 = m2 ? az[z - 2] : 0.f;
        const float azp1 = p1 ? az[z + 1] : 0.f;
        const float azp2 = p2 ? az[z + 2] : 0.f;
        F4 qzm1 = m1 ? ldf4(pzi + idx - NXP)     : zf4();
        F4 qzm2 = m2 ? ldf4(pzi + idx - 2 * NXP) : zf4();
        F4 qzp1 = p1 ? ldf4(pzi + idx + NXP)     : zf4();
        F4 qzp2 = p2 ? ldf4(pzi + idx + 2 * NXP) : zf4();
        #pragma unroll
        for (int k = 0; k < 4; ++k) {
            qzm1.f[k] *= azm1; qzm2.f[k] *= azm2;
            qzp1.f[k] *= azp1; qzp2.f[k] *= azp2;
        }

        // ---- center-cell state ----
        F4 pzC = ldf4(pzi + idx);
        F4 zzC = ldf4(zz + idx);
        F4 zxC = ldf4(zx + idx);
        F4 vC  = ldf4(v + 4 * ch);
        F4 wpC = ldf4(wp + idx);
        F4 bxC = ldf4(bx + x0);
        F4 dxC = ldf4(dbx + x0);
        const float azc = az[z], bzc = bz[z], dbzc = dbz[z];

        F4 o_w, o_pz, o_px, o_zz, o_zx;

        #pragma unroll
        for (int k = 0; k < 4; ++k) {
            const float c = wx[4 + k];
            const float d1x  = ((wx[5 + k] - wx[3 + k]) * C23 + (wx[2 + k] - wx[6 + k]) * C112) * INV_DX;
            const float d2x  = (-2.5f * c + C43 * (wx[5 + k] + wx[3 + k]) - C112 * (wx[6 + k] + wx[2 + k])) * INV_DX2;
            const float dapx = ((apx[5 + k] - apx[3 + k]) * C23 + (apx[2 + k] - apx[6 + k]) * C112) * INV_DX;
            const float d1z  = ((wzp1.f[k] - wzm1.f[k]) * C23 + (wzm2.f[k] - wzp2.f[k]) * C112) * INV_DX;
            const float d2z  = (-2.5f * c + C43 * (wzp1.f[k] + wzm1.f[k]) - C112 * (wzp2.f[k] + wzm2.f[k])) * INV_DX2;
            const float dapz = ((qzp1.f[k] - qzm1.f[k]) * C23 + (qzm2.f[k] - qzp2.f[k]) * C112) * INV_DX;

            const float tmpz = (1.f + bzc) * d2z + dbzc * d1z + dapz;
            float w_sum = (1.f + bzc) * tmpz + azc * zzC.f[k];

            const float bxk = bxC.f[k], axk = aCx.f[k];
            const float tmpx = (1.f + bxk) * d2x + dxC.f[k] * d1x + dapx;
            w_sum += (1.f + bxk) * tmpx + axk * zxC.f[k];

            const float vv = vC.f[k];
            float wn = (vv * vv) * (DT * DT) * w_sum + 2.f * c - wpC.f[k];
            if (4 * ch + k == srci) wn += amp_t;   // source injection (N_SRC==1)

            o_w.f[k]  = wn;
            o_pz.f[k] = bzc * d1z + azc * pzC.f[k];
            o_px.f[k] = bxk * d1x + apx[4 + k];
            o_zz.f[k] = bzc * tmpz + azc * zzC.f[k];
            o_zx.f[k] = bxk * tmpx + axk * zxC.f[k];
        }

        *reinterpret_cast<float4*>(wp + idx)  = o_w.v;
        *reinterpret_cast<float4*>(pzo + idx) = o_pz.v;
        *reinterpret_cast<float4*>(pxo + idx) = o_px.v;
        *reinterpret_cast<float4*>(zz + idx)  = o_zz.v;
        *reinterpret_cast<float4*>(zx + idx)  = o_zx.v;
    }
}

extern "C" void kernel_launch(void* const* d_in, const int* in_sizes, int n_in,
                              void* d_out, int out_size, void* d_ws, size_t ws_size,
                              hipStream_t stream) {
    const float* v     = (const float*)d_in[0];
    const float* amp   = (const float*)d_in[1];
    const float* az    = (const float*)d_in[2];
    const float* bz    = (const float*)d_in[3];
    const float* dbz   = (const float*)d_in[4];
    const float* ax    = (const float*)d_in[5];
    const float* bx    = (const float*)d_in[6];
    const float* dbx   = (const float*)d_in[7];
    const int* src_i   = (const int*)d_in[8];
    const int* rec_i   = (const int*)d_in[9];
    float* out = (float*)d_out;

    float* ws = (float*)d_ws;
    const size_t A = (size_t)N_SHOTS * FLAT;

    // Layout: [wf0, wf1, pz0, px0, zz, zx | pz1, px1] — first 6 need zeroing;
    // pz1/px1 are fully written at t=0 before being read.
    float* wf0 = ws + 0 * A; float* wf1 = ws + 1 * A;
    float* pz0 = ws + 2 * A; float* px0 = ws + 3 * A;
    float* zz  = ws + 4 * A; float* zx  = ws + 5 * A;
    float* pz1 = ws + 6 * A; float* px1 = ws + 7 * A;

    hipMemsetAsync(d_ws, 0, 6 * A * sizeof(float), stream);

    float* wf[2] = { wf0, wf1 };
    float* pz[2] = { pz0, pz1 };
    float* px[2] = { px0, px1 };

    int cur = 0;
    for (int t = 0; t < NT; ++t) {
        fdtd_step4<<<512, 320, 0, stream>>>(
            v, amp, az, bz, dbz, ax, bx, dbx, src_i, rec_i,
            wf[cur], wf[1 - cur],
            pz[cur], pz[1 - cur],
            px[cur], px[1 - cur],
            zz, zx, out, t);
        cur ^= 1;
    }
}